// Round 11
// baseline (512.953 us; speedup 1.0000x reference)
//
#include <hip/hip_runtime.h>
#include <hip/hip_cooperative_groups.h>
#include <cstdint>
#include <cstddef>

namespace cg = cooperative_groups;

typedef unsigned long long u64;
typedef unsigned int u32;
typedef _Float16 half8 __attribute__((ext_vector_type(8)));
typedef float f32x4 __attribute__((ext_vector_type(4)));

#define NN 2048
#define DD 512
#define EE 65536
#define NW 32   // 64-bit words per bitset row
#define BK 64

__device__ __forceinline__ float leaky(float x) { return x > 0.f ? x : 0.01f * x; }

// One cooperative kernel, 7 phases, 6 grid syncs. All phases gridDim-stride so
// any resident-safe grid works. LDS: 32KB union buffer reused per phase.
__global__ __launch_bounds__(256, 4) void k_mega(
    const float* __restrict__ emb, const int* __restrict__ ei,
    const float* __restrict__ Wsc, const float* __restrict__ bsc,
    float* __restrict__ out,
    float* __restrict__ fit, _Float16* __restrict__ zh, _Float16* __restrict__ zl,
    u64* __restrict__ A1w, u64* __restrict__ A2w, u64* __restrict__ CLw,
    u64* __restrict__ EBw, u64* centerBits, u64* colAny,
    float* ssum, float* cs, float* av, float* cv, unsigned char* is_c)
{
    cg::grid_group grid = cg::this_grid();
    __shared__ alignas(16) char SMEM[32768];
    const int b = blockIdx.x, t = threadIdx.x, G = gridDim.x;
    const int wid = t >> 6, lane = t & 63;

    // ========== Phase A: init scratch + per-node reductions + f16 split ==========
    for (int idx = b * 256 + t; idx < NN * NW; idx += G * 256) EBw[idx] = 0ull;
    for (int idx = b * 256 + t; idx < NN; idx += G * 256) ssum[idx] = 0.f;
    if (b == 0 && t < NW) { centerBits[t] = 0ull; colAny[t] = 0ull; }
    {
        float* red = (float*)SMEM;               // [3][4]
        float* s_inv = (float*)(SMEM + 64);
        for (int n = b; n < NN; n += G) {
            const float* row = emb + (size_t)n * DD;
            float ss = 0.f, aa = 0.f, cc = 0.f;
            for (int d = t; d < DD; d += 256) {
                float v = row[d];
                ss += v * v; aa += v * Wsc[d]; cc += v * Wsc[DD + d];
            }
            for (int off = 32; off; off >>= 1) {
                ss += __shfl_down(ss, off);
                aa += __shfl_down(aa, off);
                cc += __shfl_down(cc, off);
            }
            if (lane == 0) { red[wid] = ss; red[4 + wid] = aa; red[8 + wid] = cc; }
            __syncthreads();
            if (t == 0) {
                float s = 0, a = 0, c = 0;
                for (int w = 0; w < 4; w++) { s += red[w]; a += red[4 + w]; c += red[8 + w]; }
                *s_inv = 1.0f / fmaxf(sqrtf(s), 1e-12f);
                av[n] = a; cv[n] = c;
            }
            __syncthreads();
            float iv = *s_inv;
            for (int d = t; d < DD; d += 256) {
                float z = row[d] * iv;
                _Float16 h = (_Float16)z;
                _Float16 l = (_Float16)(z - (float)h);
                zh[(size_t)n * DD + d] = h;
                zl[(size_t)n * DD + d] = l;
            }
            __syncthreads();   // protect red/s_inv reuse across rows
        }
    }
    grid.sync();

    // ========== Phase B: fitness (triangular 64x64 MFMA tiles) + edge exp-sum ==========
    {
        _Float16* Ah = (_Float16*)SMEM;
        _Float16* Al = Ah + 64 * BK;
        _Float16* Bh = Ah + 2 * 64 * BK;
        _Float16* Bl = Ah + 3 * 64 * BK;
        int wr = wid >> 1, wc = wid & 1;
        int lr = lane & 15, q = lane >> 4;
        int rl0 = t >> 3, sl0 = t & 7;
        int rl1 = (256 + t) >> 3, sl1 = t & 7;
        int ks0 = ((sl0 ^ (rl0 & 7)) << 3);
        int ks1 = ((sl1 ^ (rl1 & 7)) << 3);
        int lo0 = rl0 * BK + sl0 * 8, lo1 = rl1 * BK + sl1 * 8;
        for (int p0 = b; p0 < 528; p0 += G) {
            __syncthreads();                     // protect SMEM reuse across tiles
            int p = p0, bi = 0;
            while (p >= 32 - bi) { p -= 32 - bi; bi++; }
            int bj = bi + p;
            int I = bi * 64, J = bj * 64;
            f32x4 acc[2][2] = {};
            size_t gA0 = (size_t)(I + rl0) * DD + ks0, gB0 = (size_t)(J + rl0) * DD + ks0;
            size_t gA1 = (size_t)(I + rl1) * DD + ks1, gB1 = (size_t)(J + rl1) * DD + ks1;
            {   // prologue stage k0=0
                half8 a0 = *(const half8*)&zh[gA0], a1 = *(const half8*)&zh[gA1];
                half8 l0 = *(const half8*)&zl[gA0], l1 = *(const half8*)&zl[gA1];
                half8 b0 = *(const half8*)&zh[gB0], b1 = *(const half8*)&zh[gB1];
                half8 m0 = *(const half8*)&zl[gB0], m1 = *(const half8*)&zl[gB1];
                *(half8*)&Ah[lo0] = a0; *(half8*)&Ah[lo1] = a1;
                *(half8*)&Al[lo0] = l0; *(half8*)&Al[lo1] = l1;
                *(half8*)&Bh[lo0] = b0; *(half8*)&Bh[lo1] = b1;
                *(half8*)&Bl[lo0] = m0; *(half8*)&Bl[lo1] = m1;
            }
            __syncthreads();
            for (int k0 = 0; k0 < DD; k0 += BK) {
                half8 nA0, nA1, nAl0, nAl1, nB0, nB1, nBl0, nBl1;
                bool hasNext = (k0 + BK) < DD;
                if (hasNext) {
                    int kn = k0 + BK;
                    nA0 = *(const half8*)&zh[gA0 + kn]; nA1 = *(const half8*)&zh[gA1 + kn];
                    nAl0 = *(const half8*)&zl[gA0 + kn]; nAl1 = *(const half8*)&zl[gA1 + kn];
                    nB0 = *(const half8*)&zh[gB0 + kn]; nB1 = *(const half8*)&zh[gB1 + kn];
                    nBl0 = *(const half8*)&zl[gB0 + kn]; nBl1 = *(const half8*)&zl[gB1 + kn];
                }
#pragma unroll
                for (int kk = 0; kk < 2; kk++) {
                    half8 a_h[2], a_l[2], b_h[2], b_l[2];
#pragma unroll
                    for (int f = 0; f < 2; f++) {
                        int ra = wr * 32 + f * 16 + lr;
                        int ca = (kk * 4 + q) ^ (ra & 7);
                        a_h[f] = *(const half8*)&Ah[ra * BK + ca * 8];
                        a_l[f] = *(const half8*)&Al[ra * BK + ca * 8];
                        int rb = wc * 32 + f * 16 + lr;
                        int cb = (kk * 4 + q) ^ (rb & 7);
                        b_h[f] = *(const half8*)&Bh[rb * BK + cb * 8];
                        b_l[f] = *(const half8*)&Bl[rb * BK + cb * 8];
                    }
#pragma unroll
                    for (int u = 0; u < 2; u++)
#pragma unroll
                        for (int v = 0; v < 2; v++) {
                            acc[u][v] = __builtin_amdgcn_mfma_f32_16x16x32_f16(a_h[u], b_h[v], acc[u][v], 0, 0, 0);
                            acc[u][v] = __builtin_amdgcn_mfma_f32_16x16x32_f16(a_h[u], b_l[v], acc[u][v], 0, 0, 0);
                            acc[u][v] = __builtin_amdgcn_mfma_f32_16x16x32_f16(a_l[u], b_h[v], acc[u][v], 0, 0, 0);
                        }
                }
                if (hasNext) {
                    __syncthreads();
                    *(half8*)&Ah[lo0] = nA0; *(half8*)&Ah[lo1] = nA1;
                    *(half8*)&Al[lo0] = nAl0; *(half8*)&Al[lo1] = nAl1;
                    *(half8*)&Bh[lo0] = nB0; *(half8*)&Bh[lo1] = nB1;
                    *(half8*)&Bl[lo0] = nBl0; *(half8*)&Bl[lo1] = nBl1;
                    __syncthreads();
                }
            }
            // C/D layout col=lane&15, row=(lane>>4)*4+reg (m89-verified)
#pragma unroll
            for (int u = 0; u < 2; u++) {
                int r = I + wr * 32 + u * 16 + q * 4;
#pragma unroll
                for (int v = 0; v < 2; v++) {
                    int c = J + wc * 32 + v * 16 + lr;
#pragma unroll
                    for (int i2 = 0; i2 < 4; i2++)
                        fit[(size_t)(r + i2) * NN + c] = acc[u][v][i2];
                }
            }
            if (bi != bj) {   // mirror write, exact transpose via padded LDS [16][33]
                __syncthreads();
                float* Tw = (float*)SMEM + wid * 528;
#pragma unroll
                for (int v = 0; v < 2; v++) {
#pragma unroll
                    for (int u = 0; u < 2; u++)
#pragma unroll
                        for (int i2 = 0; i2 < 4; i2++)
                            Tw[lr * 33 + u * 16 + q * 4 + i2] = acc[u][v][i2];
                    int cbase = J + wc * 32 + v * 16;
                    int rbase = I + wr * 32;
#pragma unroll
                    for (int rr = 0; rr < 8; rr++) {
                        int row = rr * 2 + (lane >> 5);
                        int col = lane & 31;
                        fit[(size_t)(cbase + row) * NN + rbase + col] = Tw[row * 33 + col];
                    }
                }
            }
        }
        // edge exp-sum + bitset (high block ids -> disjoint from fitness tiles)
        int eb = (G - 1) - b;
        float b0v = bsc[0];
        for (int e = eb * 256 + t; e < EE && e >= 0; e += G * 256) {
            int s = ei[e], d = ei[EE + e];
            float x = leaky(av[s] + cv[d] + b0v);
            atomicAdd(&ssum[s], expf(x));
            atomicOr(&EBw[(size_t)s * NW + (d >> 6)], 1ull << (d & 63));
        }
    }
    grid.sync();

    // ========== Phase C: scatter softmax weights into fit ==========
    {
        float b0v = bsc[0];
        for (int e = b * 256 + t; e < EE; e += G * 256) {
            int s = ei[e], d = ei[EE + e];
            float x = leaky(av[s] + cv[d] + b0v);
            float w = expf(x) / (ssum[s] + 1e-16f);
            atomicAdd(&fit[(size_t)s * NN + d], w);
        }
    }
    grid.sync();

    // ========== Phase D: A1 bitset ==========
    for (int i = b; i < NN; i += G) {
        int wv = t >> 6;
        for (int qq = 0; qq < 8; qq++) {
            int j = qq * 256 + t;
            u64 ebv = EBw[(size_t)i * NW + (j >> 6)];
            float f = fit[(size_t)i * NN + j];
            bool pred = ((ebv >> (j & 63)) & 1) && (j != i) && (f >= 0.f);
            u64 word = __ballot(pred);
            if (lane == 0) A1w[i * NW + qq * 4 + wv] = word;
        }
    }
    grid.sync();

    // ========== Phase E: boolean A1@A1 (A2/CL) + cluster scores ==========
    {
        u64* rowA = (u64*)SMEM;                  // 32
        u64* rowA2 = rowA + NW;                  // 32
        u64* part = rowA2 + NW;                  // [8][32]
        float* rs1 = (float*)(part + 8 * NW);
        float* rs2 = rs1 + 4;
        int* rd1 = (int*)(rs2 + 4);
        int* rd2 = rd1 + 4;
        for (int i = b; i < NN; i += G) {
            __syncthreads();
            if (t < NW) rowA[t] = A1w[i * NW + t];
            __syncthreads();
            int g = t >> 5, w = t & 31;
            u64 acc = 0;
            for (int ww = 0; ww < 4; ww++) {
                u64 bits = rowA[g * 4 + ww];
                int kbase = (g * 4 + ww) * 64;
                while (bits) {
                    int k = __ffsll((unsigned long long)bits) - 1;
                    bits &= bits - 1;
                    acc |= A1w[(size_t)(kbase + k) * NW + w];
                }
            }
            part[g * NW + w] = acc;
            __syncthreads();
            if (g == 0) {
                u64 p2 = part[w];
#pragma unroll
                for (int gg = 1; gg < 8; gg++) p2 |= part[gg * NW + w];
                if ((i >> 6) == w) p2 &= ~(1ull << (i & 63));
                u64 a1 = rowA[w];
                u64 a2 = p2 & ~a1;
                A2w[i * NW + w] = a2;
                CLw[i * NW + w] = a1 | a2;
                rowA2[w] = a2;
            }
            __syncthreads();
            float s1 = 0, s2 = 0; int d1 = 0, d2 = 0;
            for (int qq = 0; qq < 8; qq++) {
                int j = qq * 256 + t;
                float f = fit[(size_t)i * NN + j];
                int ww = j >> 6, bb = j & 63;
                if ((rowA[ww] >> bb) & 1) { s1 += f; d1++; }
                if ((rowA2[ww] >> bb) & 1) { s2 += f; d2++; }
            }
            for (int off = 32; off; off >>= 1) {
                s1 += __shfl_down(s1, off); s2 += __shfl_down(s2, off);
                d1 += __shfl_down(d1, off); d2 += __shfl_down(d2, off);
            }
            if (lane == 0) { rs1[wid] = s1; rs2[wid] = s2; rd1[wid] = d1; rd2[wid] = d2; }
            __syncthreads();
            if (t == 0) {
                float S1 = 0, S2 = 0; int D1 = 0, D2 = 0;
                for (int w2 = 0; w2 < 4; w2++) { S1 += rs1[w2]; S2 += rs2[w2]; D1 += rd1[w2]; D2 += rd2[w2]; }
                float v1 = D1 > 0 ? S1 / (float)D1 : 0.f;
                float v2 = D2 > 0 ? S2 / (float)D2 : 0.f;
                cs[i] = 0.5f * (v1 + v2);
            }
        }
    }
    grid.sync();

    // ========== Phase F: local extrema + colAny ==========
    for (int i = b; i < NN; i += G) {
        float ci = cs[i];
        int ok = 1;
        for (int qq = 0; qq < 8; qq++) {
            int j = qq * 256 + t;
            u64 a1 = A1w[i * NW + (j >> 6)];
            float other = ((a1 >> (j & 63)) & 1) ? cs[j] : 0.0f;
            ok &= ((ci - other) > 0.0f) ? 1 : 0;
        }
        int all = __syncthreads_and(ok);
        if (t == 0) {
            is_c[i] = (unsigned char)(all ? 1 : 0);
            if (all) atomicOr(&centerBits[i >> 6], 1ull << (i & 63));
        }
    }
    {
        u64* part = (u64*)SMEM;                  // [8][32]
        for (int cb2 = b; cb2 < 64; cb2 += G) {
            __syncthreads();
            int sub = t >> 5, w = t & 31;
            u64 acc = 0;
#pragma unroll
            for (int k = 0; k < 4; k++) acc |= CLw[(size_t)(cb2 * 32 + sub + k * 8) * NW + w];
            part[sub * NW + w] = acc;
            __syncthreads();
            if (t < NW) {
                u64 v = part[t];
#pragma unroll
                for (int s2 = 1; s2 < 8; s2++) v |= part[s2 * NW + t];
                atomicOr(&colAny[t], v);
            }
        }
    }
    grid.sync();

    // ========== Phase G: pooled (sparse-column M^T @ emb) ==========
    {
        int* lidx = (int*)SMEM;                  // 2048
        float* lwt = (float*)(SMEM + NN * 4);    // 2048
        int* wcnt = (int*)(SMEM + NN * 8);       // 4
        for (int j = b; j < NN; j += G) {
            __syncthreads();
            bool red = ((colAny[j >> 6] >> (j & 63)) & 1ull) == 0ull;
            for (int w = 0; w < NW; w++) red |= (CLw[(size_t)j * NW + w] & centerBits[w]) != 0ull;
            const float2* embj = (const float2*)(emb + (size_t)j * DD);
            float2* outj = (float2*)(out + (size_t)j * DD);
            bool active = is_c[j] && !red;
            if (!active) {
                float dg = red ? 0.f : 1.f;
                float2 v = embj[t];
                float2 o; o.x = v.x * dg; o.y = v.y * dg;
                outj[t] = o;
                continue;
            }
            int wsh = j >> 6;
            u64 bmask = 1ull << (j & 63);
            int total = 0;
            for (int qq = 0; qq < 8; qq++) {
                int i = qq * 256 + t;
                u64 cw = CLw[(size_t)i * NW + wsh];
                bool pp = (cw & bmask) != 0ull;
                float f = 0.f;
                if (pp) f = fit[(size_t)i * NN + j];
                u64 mask = __ballot(pp);
                if (lane == 0) wcnt[wid] = __popcll(mask);
                __syncthreads();
                int off = total;
                for (int w = 0; w < wid; w++) off += wcnt[w];
                int tq = wcnt[0] + wcnt[1] + wcnt[2] + wcnt[3];
                if (pp) {
                    int pos = off + __popcll(mask & ((1ull << lane) - 1ull));
                    lidx[pos] = i; lwt[pos] = f;
                }
                total += tq;
                __syncthreads();
            }
            float2 acc = {0.f, 0.f};
            int k = 0;
            for (; k + 16 <= total; k += 16) {
                int idxr[16]; float wtr[16];
#pragma unroll
                for (int u = 0; u < 16; u++) { idxr[u] = lidx[k + u]; wtr[u] = lwt[k + u]; }
                float2 e[16];
#pragma unroll
                for (int u = 0; u < 16; u++) e[u] = ((const float2*)(emb + (size_t)idxr[u] * DD))[t];
#pragma unroll
                for (int u = 0; u < 16; u++) { acc.x += wtr[u] * e[u].x; acc.y += wtr[u] * e[u].y; }
            }
            for (; k < total; k++) {
                int i = lidx[k]; float w = lwt[k];
                float2 e = ((const float2*)(emb + (size_t)i * DD))[t];
                acc.x += w * e.x; acc.y += w * e.y;
            }
            float2 v = embj[t];
            acc.x += v.x; acc.y += v.y;
            outj[t] = acc;
        }
    }
}

// ---------- launch ----------
extern "C" void kernel_launch(void* const* d_in, const int* in_sizes, int n_in,
                              void* d_out, int out_size, void* d_ws, size_t ws_size,
                              hipStream_t stream) {
    const float* emb = (const float*)d_in[0];
    const int*   ei  = (const int*)d_in[1];
    // d_in[2] = edge_matrix (reconstructed as bitset), d_in[3] = edge_matrix_weight (unused)
    const float* Wsc = (const float*)d_in[4];
    const float* bsc = (const float*)d_in[5];
    float* out = (float*)d_out;

    char* ws = (char*)d_ws;
    size_t off = 0;
    auto alloc = [&](size_t bytes) -> char* {
        char* p = ws + off;
        off = (off + bytes + 255) & ~(size_t)255;
        return p;
    };
    float*    fit = (float*)alloc((size_t)NN * NN * 4);        // 16 MB
    _Float16* zh  = (_Float16*)alloc((size_t)NN * DD * 2);     // 2 MB
    _Float16* zl  = (_Float16*)alloc((size_t)NN * DD * 2);     // 2 MB
    u64* A1w = (u64*)alloc((size_t)NN * NW * 8);
    u64* A2w = (u64*)alloc((size_t)NN * NW * 8);
    u64* CLw = (u64*)alloc((size_t)NN * NW * 8);
    u64* EBw = (u64*)alloc((size_t)NN * NW * 8);
    u64* centerBits = (u64*)alloc(NW * 8);
    u64* colAny     = (u64*)alloc(NW * 8);
    float* ssum = (float*)alloc(NN * 4);
    float* cs   = (float*)alloc(NN * 4);
    float* av   = (float*)alloc(NN * 4);
    float* cv   = (float*)alloc(NN * 4);
    unsigned char* is_c = (unsigned char*)alloc(NN);

    // resident-safe grid for cooperative launch (phases are gridDim-stride)
    int maxB = 0;
    hipOccupancyMaxActiveBlocksPerMultiprocessor(&maxB, (const void*)k_mega, 256, 0);
    int G = (maxB > 0) ? maxB * 256 : 512;     // 256 CUs
    if (G > 1024) G = 1024;

    void* args[] = {
        (void*)&emb, (void*)&ei, (void*)&Wsc, (void*)&bsc, (void*)&out,
        (void*)&fit, (void*)&zh, (void*)&zl,
        (void*)&A1w, (void*)&A2w, (void*)&CLw, (void*)&EBw,
        (void*)&centerBits, (void*)&colAny,
        (void*)&ssum, (void*)&cs, (void*)&av, (void*)&cv, (void*)&is_c
    };
    hipLaunchCooperativeKernel((const void*)k_mega, dim3(G), dim3(256), args, 0, stream);
}

// Round 12
// 141.060 us; speedup vs baseline: 3.6364x; 3.6364x over previous
//
#include <hip/hip_runtime.h>
#include <cstdint>
#include <cstddef>

typedef unsigned long long u64;
typedef unsigned int u32;
typedef _Float16 half8 __attribute__((ext_vector_type(8)));
typedef float f32x4 __attribute__((ext_vector_type(4)));

#define NN 2048
#define DD 512
#define EE 65536
#define NW 32   // 64-bit words per bitset row (2048/64)

// ---------- fused: init scratch + per-node reductions + f16 split ----------
__global__ __launch_bounds__(256) void k_node(const float* __restrict__ emb,
                                              const float* __restrict__ Wsc,
                                              float* inv_norm, float* av, float* cv,
                                              _Float16* __restrict__ zh,
                                              _Float16* __restrict__ zl,
                                              float* ssum,
                                              u64* centerBits, u64* colAny, u64* A1w) {
    int n = blockIdx.x;
    int t = threadIdx.x;
    if (n < 256) A1w[n * 256 + t] = 0ull;                 // zero A1 bitset (own buffer)
    else if (n < 264) { int idx = (n - 256) * 256 + t; ssum[idx] = 0.0f; }
    else if (n == 264 && t < NW) { centerBits[t] = 0ull; colAny[t] = 0ull; }

    const float* row = emb + (size_t)n * DD;
    float ss = 0.f, aa = 0.f, cc = 0.f;
    for (int d = t; d < DD; d += 256) {
        float v = row[d];
        ss += v * v;
        aa += v * Wsc[d];
        cc += v * Wsc[DD + d];
    }
    for (int off = 32; off; off >>= 1) {
        ss += __shfl_down(ss, off);
        aa += __shfl_down(aa, off);
        cc += __shfl_down(cc, off);
    }
    __shared__ float red[3][4];
    __shared__ float s_inv;
    int wid = t >> 6, lane = t & 63;
    if (lane == 0) { red[0][wid] = ss; red[1][wid] = aa; red[2][wid] = cc; }
    __syncthreads();
    if (t == 0) {
        float s = 0.f, a = 0.f, c = 0.f;
        for (int w = 0; w < 4; w++) { s += red[0][w]; a += red[1][w]; c += red[2][w]; }
        float iv = 1.0f / fmaxf(sqrtf(s), 1e-12f);
        inv_norm[n] = iv;
        s_inv = iv;
        av[n] = a;
        cv[n] = c;
    }
    __syncthreads();
    float iv = s_inv;
    for (int d = t; d < DD; d += 256) {
        float z = row[d] * iv;
        _Float16 h = (_Float16)z;
        _Float16 l = (_Float16)(z - (float)h);
        zh[(size_t)n * DD + d] = h;
        zl[(size_t)n * DD + d] = l;
    }
}

// ---------- edge passes (max-free softmax: exp(x)/sum, |x|<~6 so safe) ----------
__device__ __forceinline__ float edge_score(const int* ei, const float* av, const float* cv,
                                            float b0, int e, int* src, int* dst) {
    int s = ei[e], d = ei[EE + e];
    *src = s; *dst = d;
    float x = av[s] + cv[d] + b0;
    return x > 0.f ? x : 0.01f * x;   // leaky_relu
}

// edge exp-sum
__global__ __launch_bounds__(256) void k_edgeA(const int* __restrict__ ei,
                                               const float* __restrict__ av,
                                               const float* __restrict__ cv,
                                               const float* __restrict__ bsc,
                                               float* ssum) {
    int e = blockIdx.x * 256 + threadIdx.x;
    if (e >= EE) return;
    int s, d;
    float x = edge_score(ei, av, cv, bsc[0], e, &s, &d);
    atomicAdd(&ssum[s], expf(x));
}

__global__ __launch_bounds__(256) void k_edge_scatter(const int* __restrict__ ei,
                                                      const float* __restrict__ av,
                                                      const float* __restrict__ cv,
                                                      const float* __restrict__ bsc,
                                                      const float* __restrict__ ssum,
                                                      float* fit) {
    int e = blockIdx.x * 256 + threadIdx.x;
    if (e >= EE) return;
    int s, d;
    float x = edge_score(ei, av, cv, bsc[0], e, &s, &d);
    float w = expf(x) / (ssum[s] + 1e-16f);
    atomicAdd(&fit[(size_t)s * NN + d], w);
}

// ---------- A1 bits in edge space: edge && !diag && fit>=0 (post-scatter) ----------
__global__ __launch_bounds__(256) void k_bits_e(const int* __restrict__ ei,
                                                const float* __restrict__ fit,
                                                u64* __restrict__ A1w) {
    int e = blockIdx.x * 256 + threadIdx.x;
    if (e >= EE) return;
    int s = ei[e], d = ei[EE + e];
    if (s == d) return;
    float f = fit[(size_t)s * NN + d];
    if (f >= 0.f)
        atomicOr(&A1w[(size_t)s * NW + (d >> 6)], 1ull << (d & 63));
}

// ---------- fitness = Z Z^T via f16-split triple MFMA, SYMMETRIC 64x64 tiles ----------
// 528 blocks (32x33/2 upper-triangle), 256 thr (4 waves, 2x2 of 32x32), 32KB LDS.
#define BK 64
__global__ __launch_bounds__(256) void k_fitness(const _Float16* __restrict__ zh,
                                                 const _Float16* __restrict__ zl,
                                                 float* __restrict__ fit) {
    __shared__ _Float16 SM[4 * 64 * BK];        // 32 KB, reused for transpose
    _Float16* Ah = SM;
    _Float16* Al = SM + 64 * BK;
    _Float16* Bh = SM + 2 * 64 * BK;
    _Float16* Bl = SM + 3 * 64 * BK;
    int tid = threadIdx.x;
    int wid = tid >> 6, lane = tid & 63;
    int wr = wid >> 1, wc = wid & 1;           // wave 2x2 grid of 32x32 sub-tiles
    // triangular tile decode: blockIdx.x -> (bi, bj), bi <= bj, 32 tile-rows
    int p = blockIdx.x, bi = 0;
    while (p >= 32 - bi) { p -= 32 - bi; bi++; }
    int bj = bi + p;
    int I = bi * 64, J = bj * 64;
    int lr = lane & 15;                        // frag row/col
    int q = lane >> 4;                         // k-group 0..3
    f32x4 acc[2][2] = {};

    // staging: 64 rows x 8 slots = 512 slots -> 2 chunks of 256 threads
    int rl0 = tid >> 3, sl0 = tid & 7;                 // chunk 0 (rows 0..31)
    int rl1 = (256 + tid) >> 3, sl1 = tid & 7;         // chunk 1 (rows 32..63)
    int ks0 = ((sl0 ^ (rl0 & 7)) << 3);
    int ks1 = ((sl1 ^ (rl1 & 7)) << 3);
    size_t gA0 = (size_t)(I + rl0) * DD + ks0, gB0 = (size_t)(J + rl0) * DD + ks0;
    size_t gA1 = (size_t)(I + rl1) * DD + ks1, gB1 = (size_t)(J + rl1) * DD + ks1;
    int lo0 = rl0 * BK + sl0 * 8, lo1 = rl1 * BK + sl1 * 8;

    {   // prologue: stage k0 = 0
        half8 a0 = *reinterpret_cast<const half8*>(&zh[gA0]);
        half8 a1 = *reinterpret_cast<const half8*>(&zh[gA1]);
        half8 l0 = *reinterpret_cast<const half8*>(&zl[gA0]);
        half8 l1 = *reinterpret_cast<const half8*>(&zl[gA1]);
        half8 b0 = *reinterpret_cast<const half8*>(&zh[gB0]);
        half8 b1 = *reinterpret_cast<const half8*>(&zh[gB1]);
        half8 m0 = *reinterpret_cast<const half8*>(&zl[gB0]);
        half8 m1 = *reinterpret_cast<const half8*>(&zl[gB1]);
        *reinterpret_cast<half8*>(&Ah[lo0]) = a0;
        *reinterpret_cast<half8*>(&Ah[lo1]) = a1;
        *reinterpret_cast<half8*>(&Al[lo0]) = l0;
        *reinterpret_cast<half8*>(&Al[lo1]) = l1;
        *reinterpret_cast<half8*>(&Bh[lo0]) = b0;
        *reinterpret_cast<half8*>(&Bh[lo1]) = b1;
        *reinterpret_cast<half8*>(&Bl[lo0]) = m0;
        *reinterpret_cast<half8*>(&Bl[lo1]) = m1;
    }
    __syncthreads();

    for (int k0 = 0; k0 < DD; k0 += BK) {
        half8 nA0, nA1, nAl0, nAl1, nB0, nB1, nBl0, nBl1;
        bool hasNext = (k0 + BK) < DD;
        if (hasNext) {
            int kn = k0 + BK;
            nA0  = *reinterpret_cast<const half8*>(&zh[gA0 + kn]);
            nA1  = *reinterpret_cast<const half8*>(&zh[gA1 + kn]);
            nAl0 = *reinterpret_cast<const half8*>(&zl[gA0 + kn]);
            nAl1 = *reinterpret_cast<const half8*>(&zl[gA1 + kn]);
            nB0  = *reinterpret_cast<const half8*>(&zh[gB0 + kn]);
            nB1  = *reinterpret_cast<const half8*>(&zh[gB1 + kn]);
            nBl0 = *reinterpret_cast<const half8*>(&zl[gB0 + kn]);
            nBl1 = *reinterpret_cast<const half8*>(&zl[gB1 + kn]);
        }
#pragma unroll
        for (int kk = 0; kk < 2; kk++) {
            half8 a_h[2], a_l[2], b_h[2], b_l[2];
#pragma unroll
            for (int f = 0; f < 2; f++) {
                int ra = wr * 32 + f * 16 + lr;
                int ca = (kk * 4 + q) ^ (ra & 7);
                int oa = ra * BK + ca * 8;
                a_h[f] = *reinterpret_cast<const half8*>(&Ah[oa]);
                a_l[f] = *reinterpret_cast<const half8*>(&Al[oa]);
                int rb = wc * 32 + f * 16 + lr;
                int cb = (kk * 4 + q) ^ (rb & 7);
                int ob = rb * BK + cb * 8;
                b_h[f] = *reinterpret_cast<const half8*>(&Bh[ob]);
                b_l[f] = *reinterpret_cast<const half8*>(&Bl[ob]);
            }
#pragma unroll
            for (int u = 0; u < 2; u++)
#pragma unroll
                for (int v = 0; v < 2; v++) {
                    acc[u][v] = __builtin_amdgcn_mfma_f32_16x16x32_f16(a_h[u], b_h[v], acc[u][v], 0, 0, 0);
                    acc[u][v] = __builtin_amdgcn_mfma_f32_16x16x32_f16(a_h[u], b_l[v], acc[u][v], 0, 0, 0);
                    acc[u][v] = __builtin_amdgcn_mfma_f32_16x16x32_f16(a_l[u], b_h[v], acc[u][v], 0, 0, 0);
                }
        }
        if (hasNext) {
            __syncthreads();
            *reinterpret_cast<half8*>(&Ah[lo0]) = nA0;
            *reinterpret_cast<half8*>(&Ah[lo1]) = nA1;
            *reinterpret_cast<half8*>(&Al[lo0]) = nAl0;
            *reinterpret_cast<half8*>(&Al[lo1]) = nAl1;
            *reinterpret_cast<half8*>(&Bh[lo0]) = nB0;
            *reinterpret_cast<half8*>(&Bh[lo1]) = nB1;
            *reinterpret_cast<half8*>(&Bl[lo0]) = nBl0;
            *reinterpret_cast<half8*>(&Bl[lo1]) = nBl1;
            __syncthreads();
        }
    }
    // normal write: C/D layout col=lane&15, row=(lane>>4)*4+reg (m89-verified)
#pragma unroll
    for (int u = 0; u < 2; u++) {
        int r = I + wr * 32 + u * 16 + q * 4;
#pragma unroll
        for (int v = 0; v < 2; v++) {
            int c = J + wc * 32 + v * 16 + lr;
#pragma unroll
            for (int i2 = 0; i2 < 4; i2++)
                fit[(size_t)(r + i2) * NN + c] = acc[u][v][i2];
        }
    }
    // mirror write (exact transpose) via per-wave padded LDS transpose [16][33]
    if (bi != bj) {
        __syncthreads();                         // all waves done with staging LDS
        float* Tw = reinterpret_cast<float*>(SM) + wid * 528;   // 16*33 floats/wave
#pragma unroll
        for (int v = 0; v < 2; v++) {
#pragma unroll
            for (int u = 0; u < 2; u++)
#pragma unroll
                for (int i2 = 0; i2 < 4; i2++)
                    Tw[lr * 33 + u * 16 + q * 4 + i2] = acc[u][v][i2];
            int cbase = J + wc * 32 + v * 16;
            int rbase = I + wr * 32;
#pragma unroll
            for (int rr = 0; rr < 8; rr++) {
                int row = rr * 2 + (lane >> 5);
                int col = lane & 31;
                fit[(size_t)(cbase + row) * NN + rbase + col] = Tw[row * 33 + col];
            }
        }
    }
}

// ---------- fused: boolean A1@A1 (A2/CL) + cluster scores ----------
__global__ __launch_bounds__(256) void k_paths2s(const u64* __restrict__ A1w,
                                                 const float* __restrict__ fit,
                                                 u64* __restrict__ A2w, u64* __restrict__ CLw,
                                                 float* cs) {
    int i = blockIdx.x;
    __shared__ u64 rowA[NW];
    __shared__ u64 rowA2[NW];
    __shared__ u64 part[8][NW];
    int t = threadIdx.x;
    if (t < NW) rowA[t] = A1w[i * NW + t];
    __syncthreads();
    int g = t >> 5, w = t & 31;
    u64 acc = 0;
    for (int ww = 0; ww < 4; ww++) {
        u64 bits = rowA[g * 4 + ww];
        int kbase = (g * 4 + ww) * 64;
        while (bits) {
            int k = __ffsll((unsigned long long)bits) - 1;
            bits &= bits - 1;
            acc |= A1w[(size_t)(kbase + k) * NW + w];
        }
    }
    part[g][w] = acc;
    __syncthreads();
    if (g == 0) {
        u64 p2 = part[0][w];
#pragma unroll
        for (int gg = 1; gg < 8; gg++) p2 |= part[gg][w];
        if ((i >> 6) == w) p2 &= ~(1ull << (i & 63));   // zero diagonal of A1@A1
        u64 a1 = rowA[w];
        u64 a2 = p2 & ~a1;
        u64 cl = a1 | a2;
        A2w[i * NW + w] = a2;
        CLw[i * NW + w] = cl;
        rowA2[w] = a2;
    }
    __syncthreads();
    float s1 = 0.f, s2 = 0.f;
    int d1 = 0, d2 = 0;
    for (int q = 0; q < 8; q++) {
        int j = q * 256 + t;
        float f = fit[(size_t)i * NN + j];
        int ww = j >> 6, b = j & 63;
        u64 a1 = rowA[ww], a2 = rowA2[ww];
        if ((a1 >> b) & 1) { s1 += f; d1++; }
        if ((a2 >> b) & 1) { s2 += f; d2++; }
    }
    for (int off = 32; off; off >>= 1) {
        s1 += __shfl_down(s1, off);
        s2 += __shfl_down(s2, off);
        d1 += __shfl_down(d1, off);
        d2 += __shfl_down(d2, off);
    }
    __shared__ float rs1[4], rs2[4];
    __shared__ int rd1[4], rd2[4];
    int wid = t >> 6, lane = t & 63;
    if (lane == 0) { rs1[wid] = s1; rs2[wid] = s2; rd1[wid] = d1; rd2[wid] = d2; }
    __syncthreads();
    if (t == 0) {
        float S1 = 0.f, S2 = 0.f; int D1 = 0, D2 = 0;
        for (int w2 = 0; w2 < 4; w2++) { S1 += rs1[w2]; S2 += rs2[w2]; D1 += rd1[w2]; D2 += rd2[w2]; }
        float v1 = D1 > 0 ? S1 / (float)D1 : 0.f;
        float v2 = D2 > 0 ? S2 / (float)D2 : 0.f;
        cs[i] = 0.5f * (v1 + v2);
    }
}

// ---------- fused: local extrema + colAny reduction ----------
__global__ __launch_bounds__(256) void k_extcol(const u64* __restrict__ A1w,
                                                const u64* __restrict__ CLw,
                                                const float* __restrict__ cs,
                                                unsigned char* is_c, u64* centerBits,
                                                u64* colAny) {
    int i = blockIdx.x, t = threadIdx.x;
    __shared__ u64 part[8][NW];
    if (i < 64) {
        int sub = t >> 5, w = t & 31;
        u64 acc = 0;
#pragma unroll
        for (int k = 0; k < 4; k++) {
            int r = i * 32 + sub + k * 8;
            acc |= CLw[(size_t)r * NW + w];
        }
        part[sub][w] = acc;
    }
    float ci = cs[i];
    int ok = 1;
    for (int q = 0; q < 8; q++) {
        int j = q * 256 + t;
        u64 a1 = A1w[i * NW + (j >> 6)];
        float other = ((a1 >> (j & 63)) & 1) ? cs[j] : 0.0f;
        ok &= ((ci - other) > 0.0f) ? 1 : 0;
    }
    int all = __syncthreads_and(ok);
    if (t == 0) {
        is_c[i] = (unsigned char)(all ? 1 : 0);
        if (all) atomicOr(&centerBits[i >> 6], 1ull << (i & 63));
    }
    if (i < 64 && t < NW) {
        u64 v = part[0][t];
#pragma unroll
        for (int s = 1; s < 8; s++) v |= part[s][t];
        atomicOr(&colAny[t], v);
    }
}

// ---------- pooled: sparse-column M^T @ emb, 16-deep prefetch gather ----------
__global__ __launch_bounds__(256) void k_pooled(const float* __restrict__ fit,
                                                const float* __restrict__ emb,
                                                const u64* __restrict__ CLw,
                                                const u64* __restrict__ centerBits,
                                                const u64* __restrict__ colAny,
                                                const unsigned char* __restrict__ is_c,
                                                float* __restrict__ out) {
    int j = blockIdx.x;
    int t = threadIdx.x;
    bool red = ((colAny[j >> 6] >> (j & 63)) & 1ull) == 0ull;
    for (int w = 0; w < NW; w++) red |= (CLw[(size_t)j * NW + w] & centerBits[w]) != 0ull;
    const float2* embj = reinterpret_cast<const float2*>(emb + (size_t)j * DD);
    float2* outj = reinterpret_cast<float2*>(out + (size_t)j * DD);
    bool active = is_c[j] && !red;
    if (!active) {
        float dg = red ? 0.0f : 1.0f;
        float2 v = embj[t];
        float2 o; o.x = v.x * dg; o.y = v.y * dg;
        outj[t] = o;
        return;
    }
    __shared__ int lidx[NN];
    __shared__ float lwt[NN];
    __shared__ int wcnt[4];
    int wid = t >> 6, lane = t & 63;
    int wsh = j >> 6;
    u64 bmask = 1ull << (j & 63);
    int total = 0;
    for (int qq = 0; qq < 8; qq++) {
        int i = qq * 256 + t;
        u64 cw = CLw[(size_t)i * NW + wsh];
        bool p = (cw & bmask) != 0ull;
        float f = 0.f;
        if (p) f = fit[(size_t)i * NN + j];
        u64 mask = __ballot(p);
        if (lane == 0) wcnt[wid] = __popcll(mask);
        __syncthreads();
        int off = total;
        for (int w = 0; w < wid; w++) off += wcnt[w];
        int tq = wcnt[0] + wcnt[1] + wcnt[2] + wcnt[3];
        if (p) {
            int pos = off + __popcll(mask & ((1ull << lane) - 1ull));
            lidx[pos] = i;
            lwt[pos] = f;
        }
        total += tq;
        __syncthreads();
    }
    float2 acc = {0.f, 0.f};
    int k = 0;
    for (; k + 16 <= total; k += 16) {
        int idxr[16];
        float wtr[16];
#pragma unroll
        for (int u = 0; u < 16; u++) { idxr[u] = lidx[k + u]; wtr[u] = lwt[k + u]; }
        float2 e[16];
#pragma unroll
        for (int u = 0; u < 16; u++)
            e[u] = reinterpret_cast<const float2*>(emb + (size_t)idxr[u] * DD)[t];
#pragma unroll
        for (int u = 0; u < 16; u++) {
            acc.x += wtr[u] * e[u].x;
            acc.y += wtr[u] * e[u].y;
        }
    }
    for (; k < total; k++) {
        int i = lidx[k];
        float w = lwt[k];
        float2 e = reinterpret_cast<const float2*>(emb + (size_t)i * DD)[t];
        acc.x += w * e.x;
        acc.y += w * e.y;
    }
    float2 v = embj[t];
    acc.x += v.x;
    acc.y += v.y;
    outj[t] = acc;
}

// ---------- launch ----------
extern "C" void kernel_launch(void* const* d_in, const int* in_sizes, int n_in,
                              void* d_out, int out_size, void* d_ws, size_t ws_size,
                              hipStream_t stream) {
    const float* emb = (const float*)d_in[0];
    const int*   ei  = (const int*)d_in[1];
    // d_in[2] = edge_matrix (A1 computed from edge_index directly)
    // d_in[3] = edge_matrix_weight (unused by reference math)
    const float* Wsc = (const float*)d_in[4];
    const float* bsc = (const float*)d_in[5];
    float* out = (float*)d_out;

    char* ws = (char*)d_ws;
    size_t off = 0;
    auto alloc = [&](size_t bytes) -> char* {
        char* p = ws + off;
        off = (off + bytes + 255) & ~(size_t)255;
        return p;
    };
    float*    fit = (float*)alloc((size_t)NN * NN * 4);        // 16 MB
    _Float16* zh  = (_Float16*)alloc((size_t)NN * DD * 2);     // 2 MB
    _Float16* zl  = (_Float16*)alloc((size_t)NN * DD * 2);     // 2 MB
    u64* A1w = (u64*)alloc((size_t)NN * NW * 8);               // 0.5 MB (no alias)
    u64* A2w = (u64*)alloc((size_t)NN * NW * 8);
    u64* CLw = (u64*)alloc((size_t)NN * NW * 8);
    u64* centerBits = (u64*)alloc(NW * 8);
    u64* colAny     = (u64*)alloc(NW * 8);
    float* inv_norm = (float*)alloc(NN * 4);
    float* av   = (float*)alloc(NN * 4);
    float* cv   = (float*)alloc(NN * 4);
    float* ssum = (float*)alloc(NN * 4);
    float* cs   = (float*)alloc(NN * 4);
    unsigned char* is_c = (unsigned char*)alloc(NN);

    k_node<<<dim3(NN), dim3(256), 0, stream>>>(emb, Wsc, inv_norm, av, cv, zh, zl,
                                               ssum, centerBits, colAny, A1w);
    k_edgeA<<<dim3(EE / 256), dim3(256), 0, stream>>>(ei, av, cv, bsc, ssum);
    k_fitness<<<dim3(528), dim3(256), 0, stream>>>(zh, zl, fit);
    k_edge_scatter<<<dim3(EE / 256), dim3(256), 0, stream>>>(ei, av, cv, bsc, ssum, fit);
    k_bits_e<<<dim3(EE / 256), dim3(256), 0, stream>>>(ei, fit, A1w);
    k_paths2s<<<dim3(NN), dim3(256), 0, stream>>>(A1w, fit, A2w, CLw, cs);
    k_extcol<<<dim3(NN), dim3(256), 0, stream>>>(A1w, CLw, cs, is_c, centerBits, colAny);
    k_pooled<<<dim3(NN), dim3(256), 0, stream>>>(fit, emb, CLw, centerBits, colAny, is_c, out);
}

// Round 14
// 136.757 us; speedup vs baseline: 3.7508x; 1.0315x over previous
//
#include <hip/hip_runtime.h>
#include <cstdint>
#include <cstddef>

typedef unsigned long long u64;
typedef unsigned int u32;
typedef _Float16 half8 __attribute__((ext_vector_type(8)));
typedef float f32x4 __attribute__((ext_vector_type(4)));

#define NN 2048
#define DD 512
#define EE 65536
#define NW 32   // 64-bit words per bitset row (2048/64)

// ---------- fused: init scratch + per-node reductions + f16 split ----------
__global__ __launch_bounds__(256) void k_node(const float* __restrict__ emb,
                                              const float* __restrict__ Wsc,
                                              float* inv_norm, float* av, float* cv,
                                              _Float16* __restrict__ zh,
                                              _Float16* __restrict__ zl,
                                              float* ssum,
                                              u64* centerBits, u64* colAny, u64* A1w) {
    int n = blockIdx.x;
    int t = threadIdx.x;
    if (n < 256) A1w[n * 256 + t] = 0ull;                 // zero A1 bitset
    else if (n < 264) { int idx = (n - 256) * 256 + t; ssum[idx] = 0.0f; }
    else if (n == 264 && t < NW) { centerBits[t] = 0ull; colAny[t] = 0ull; }

    const float* row = emb + (size_t)n * DD;
    float ss = 0.f, aa = 0.f, cc = 0.f;
    for (int d = t; d < DD; d += 256) {
        float v = row[d];
        ss += v * v;
        aa += v * Wsc[d];
        cc += v * Wsc[DD + d];
    }
    for (int off = 32; off; off >>= 1) {
        ss += __shfl_down(ss, off);
        aa += __shfl_down(aa, off);
        cc += __shfl_down(cc, off);
    }
    __shared__ float red[3][4];
    __shared__ float s_inv;
    int wid = t >> 6, lane = t & 63;
    if (lane == 0) { red[0][wid] = ss; red[1][wid] = aa; red[2][wid] = cc; }
    __syncthreads();
    if (t == 0) {
        float s = 0.f, a = 0.f, c = 0.f;
        for (int w = 0; w < 4; w++) { s += red[0][w]; a += red[1][w]; c += red[2][w]; }
        float iv = 1.0f / fmaxf(sqrtf(s), 1e-12f);
        inv_norm[n] = iv;
        s_inv = iv;
        av[n] = a;
        cv[n] = c;
    }
    __syncthreads();
    float iv = s_inv;
    for (int d = t; d < DD; d += 256) {
        float z = row[d] * iv;
        _Float16 h = (_Float16)z;
        _Float16 l = (_Float16)(z - (float)h);
        zh[(size_t)n * DD + d] = h;
        zl[(size_t)n * DD + d] = l;
    }
}

// ---------- edge helpers (max-free softmax: exp(x)/sum, |x|<~6 so safe) ----------
__device__ __forceinline__ float edge_score(const int* ei, const float* av, const float* cv,
                                            float b0, int e, int* src, int* dst) {
    int s = ei[e], d = ei[EE + e];
    *src = s; *dst = d;
    float x = av[s] + cv[d] + b0;
    return x > 0.f ? x : 0.01f * x;   // leaky_relu
}

__global__ __launch_bounds__(256) void k_edge_scatter(const int* __restrict__ ei,
                                                      const float* __restrict__ av,
                                                      const float* __restrict__ cv,
                                                      const float* __restrict__ bsc,
                                                      const float* __restrict__ ssum,
                                                      float* fit) {
    int e = blockIdx.x * 256 + threadIdx.x;
    if (e >= EE) return;
    int s, d;
    float x = edge_score(ei, av, cv, bsc[0], e, &s, &d);
    float w = expf(x) / (ssum[s] + 1e-16f);
    atomicAdd(&fit[(size_t)s * NN + d], w);
}

// ---------- A1 bits in edge space: edge && !diag && fit>=0 (post-scatter) ----------
__global__ __launch_bounds__(256) void k_bits_e(const int* __restrict__ ei,
                                                const float* __restrict__ fit,
                                                u64* __restrict__ A1w) {
    int e = blockIdx.x * 256 + threadIdx.x;
    if (e >= EE) return;
    int s = ei[e], d = ei[EE + e];
    if (s == d) return;
    float f = fit[(size_t)s * NN + d];
    if (f >= 0.f)
        atomicOr(&A1w[(size_t)s * NW + (d >> 6)], 1ull << (d & 63));
}

// ---------- hybrid: fitness (triangular 64x64 MFMA tiles, blocks 0..527)
//            + edge exp-sum (blocks 528..783) ----------
#define BK 64
__global__ __launch_bounds__(256) void k_fitedge(const _Float16* __restrict__ zh,
                                                 const _Float16* __restrict__ zl,
                                                 float* __restrict__ fit,
                                                 const int* __restrict__ ei,
                                                 const float* __restrict__ av,
                                                 const float* __restrict__ cv,
                                                 const float* __restrict__ bsc,
                                                 float* ssum) {
    if (blockIdx.x >= 528) {
        // -------- edge exp-sum branch --------
        int e = (blockIdx.x - 528) * 256 + threadIdx.x;
        if (e < EE) {
            int s, d;
            float x = edge_score(ei, av, cv, bsc[0], e, &s, &d);
            atomicAdd(&ssum[s], expf(x));
        }
        return;
    }
    // -------- fitness tile branch --------
    __shared__ _Float16 SM[4 * 64 * BK];        // 32 KB, reused for transpose
    _Float16* Ah = SM;
    _Float16* Al = SM + 64 * BK;
    _Float16* Bh = SM + 2 * 64 * BK;
    _Float16* Bl = SM + 3 * 64 * BK;
    int tid = threadIdx.x;
    int wid = tid >> 6, lane = tid & 63;
    int wr = wid >> 1, wc = wid & 1;           // wave 2x2 grid of 32x32 sub-tiles
    int p = blockIdx.x, bi = 0;
    while (p >= 32 - bi) { p -= 32 - bi; bi++; }
    int bj = bi + p;
    int I = bi * 64, J = bj * 64;
    int lr = lane & 15;                        // frag row/col
    int q = lane >> 4;                         // k-group 0..3
    f32x4 acc[2][2] = {};

    int rl0 = tid >> 3, sl0 = tid & 7;                 // chunk 0 (rows 0..31)
    int rl1 = (256 + tid) >> 3, sl1 = tid & 7;         // chunk 1 (rows 32..63)
    int ks0 = ((sl0 ^ (rl0 & 7)) << 3);
    int ks1 = ((sl1 ^ (rl1 & 7)) << 3);
    size_t gA0 = (size_t)(I + rl0) * DD + ks0, gB0 = (size_t)(J + rl0) * DD + ks0;
    size_t gA1 = (size_t)(I + rl1) * DD + ks1, gB1 = (size_t)(J + rl1) * DD + ks1;
    int lo0 = rl0 * BK + sl0 * 8, lo1 = rl1 * BK + sl1 * 8;

    {   // prologue: stage k0 = 0
        half8 a0 = *reinterpret_cast<const half8*>(&zh[gA0]);
        half8 a1 = *reinterpret_cast<const half8*>(&zh[gA1]);
        half8 l0 = *reinterpret_cast<const half8*>(&zl[gA0]);
        half8 l1 = *reinterpret_cast<const half8*>(&zl[gA1]);
        half8 b0 = *reinterpret_cast<const half8*>(&zh[gB0]);
        half8 b1 = *reinterpret_cast<const half8*>(&zh[gB1]);
        half8 m0 = *reinterpret_cast<const half8*>(&zl[gB0]);
        half8 m1 = *reinterpret_cast<const half8*>(&zl[gB1]);
        *reinterpret_cast<half8*>(&Ah[lo0]) = a0;
        *reinterpret_cast<half8*>(&Ah[lo1]) = a1;
        *reinterpret_cast<half8*>(&Al[lo0]) = l0;
        *reinterpret_cast<half8*>(&Al[lo1]) = l1;
        *reinterpret_cast<half8*>(&Bh[lo0]) = b0;
        *reinterpret_cast<half8*>(&Bh[lo1]) = b1;
        *reinterpret_cast<half8*>(&Bl[lo0]) = m0;
        *reinterpret_cast<half8*>(&Bl[lo1]) = m1;
    }
    __syncthreads();

    for (int k0 = 0; k0 < DD; k0 += BK) {
        half8 nA0, nA1, nAl0, nAl1, nB0, nB1, nBl0, nBl1;
        bool hasNext = (k0 + BK) < DD;
        if (hasNext) {
            int kn = k0 + BK;
            nA0  = *reinterpret_cast<const half8*>(&zh[gA0 + kn]);
            nA1  = *reinterpret_cast<const half8*>(&zh[gA1 + kn]);
            nAl0 = *reinterpret_cast<const half8*>(&zl[gA0 + kn]);
            nAl1 = *reinterpret_cast<const half8*>(&zl[gA1 + kn]);
            nB0  = *reinterpret_cast<const half8*>(&zh[gB0 + kn]);
            nB1  = *reinterpret_cast<const half8*>(&zh[gB1 + kn]);
            nBl0 = *reinterpret_cast<const half8*>(&zl[gB0 + kn]);
            nBl1 = *reinterpret_cast<const half8*>(&zl[gB1 + kn]);
        }
#pragma unroll
        for (int kk = 0; kk < 2; kk++) {
            half8 a_h[2], a_l[2], b_h[2], b_l[2];
#pragma unroll
            for (int f = 0; f < 2; f++) {
                int ra = wr * 32 + f * 16 + lr;
                int ca = (kk * 4 + q) ^ (ra & 7);
                int oa = ra * BK + ca * 8;
                a_h[f] = *reinterpret_cast<const half8*>(&Ah[oa]);
                a_l[f] = *reinterpret_cast<const half8*>(&Al[oa]);
                int rb = wc * 32 + f * 16 + lr;
                int cb = (kk * 4 + q) ^ (rb & 7);
                int ob = rb * BK + cb * 8;
                b_h[f] = *reinterpret_cast<const half8*>(&Bh[ob]);
                b_l[f] = *reinterpret_cast<const half8*>(&Bl[ob]);
            }
#pragma unroll
            for (int u = 0; u < 2; u++)
#pragma unroll
                for (int v = 0; v < 2; v++) {
                    acc[u][v] = __builtin_amdgcn_mfma_f32_16x16x32_f16(a_h[u], b_h[v], acc[u][v], 0, 0, 0);
                    acc[u][v] = __builtin_amdgcn_mfma_f32_16x16x32_f16(a_h[u], b_l[v], acc[u][v], 0, 0, 0);
                    acc[u][v] = __builtin_amdgcn_mfma_f32_16x16x32_f16(a_l[u], b_h[v], acc[u][v], 0, 0, 0);
                }
        }
        if (hasNext) {
            __syncthreads();
            *reinterpret_cast<half8*>(&Ah[lo0]) = nA0;
            *reinterpret_cast<half8*>(&Ah[lo1]) = nA1;
            *reinterpret_cast<half8*>(&Al[lo0]) = nAl0;
            *reinterpret_cast<half8*>(&Al[lo1]) = nAl1;
            *reinterpret_cast<half8*>(&Bh[lo0]) = nB0;
            *reinterpret_cast<half8*>(&Bh[lo1]) = nB1;
            *reinterpret_cast<half8*>(&Bl[lo0]) = nBl0;
            *reinterpret_cast<half8*>(&Bl[lo1]) = nBl1;
            __syncthreads();
        }
    }
    // normal write: C/D layout col=lane&15, row=(lane>>4)*4+reg (m89-verified)
#pragma unroll
    for (int u = 0; u < 2; u++) {
        int r = I + wr * 32 + u * 16 + q * 4;
#pragma unroll
        for (int v = 0; v < 2; v++) {
            int c = J + wc * 32 + v * 16 + lr;
#pragma unroll
            for (int i2 = 0; i2 < 4; i2++)
                fit[(size_t)(r + i2) * NN + c] = acc[u][v][i2];
        }
    }
    // mirror write (exact transpose) via per-wave padded LDS transpose [16][33]
    if (bi != bj) {
        __syncthreads();                         // all waves done with staging LDS
        float* Tw = reinterpret_cast<float*>(SM) + wid * 528;   // 16*33 floats/wave
#pragma unroll
        for (int v = 0; v < 2; v++) {
#pragma unroll
            for (int u = 0; u < 2; u++)
#pragma unroll
                for (int i2 = 0; i2 < 4; i2++)
                    Tw[lr * 33 + u * 16 + q * 4 + i2] = acc[u][v][i2];
            int cbase = J + wc * 32 + v * 16;
            int rbase = I + wr * 32;
#pragma unroll
            for (int rr = 0; rr < 8; rr++) {
                int row = rr * 2 + (lane >> 5);
                int col = lane & 31;
                fit[(size_t)(cbase + row) * NN + rbase + col] = Tw[row * 33 + col];
            }
        }
    }
}

// ---------- fused: boolean A1@A1 (A2/CL) + cluster scores ----------
__global__ __launch_bounds__(256) void k_paths2s(const u64* __restrict__ A1w,
                                                 const float* __restrict__ fit,
                                                 u64* __restrict__ A2w, u64* __restrict__ CLw,
                                                 float* cs) {
    int i = blockIdx.x;
    __shared__ u64 rowA[NW];
    __shared__ u64 rowA2[NW];
    __shared__ u64 part[8][NW];
    int t = threadIdx.x;
    if (t < NW) rowA[t] = A1w[i * NW + t];
    __syncthreads();
    int g = t >> 5, w = t & 31;
    u64 acc = 0;
    for (int ww = 0; ww < 4; ww++) {
        u64 bits = rowA[g * 4 + ww];
        int kbase = (g * 4 + ww) * 64;
        while (bits) {
            int k = __ffsll((unsigned long long)bits) - 1;
            bits &= bits - 1;
            acc |= A1w[(size_t)(kbase + k) * NW + w];
        }
    }
    part[g][w] = acc;
    __syncthreads();
    if (g == 0) {
        u64 p2 = part[0][w];
#pragma unroll
        for (int gg = 1; gg < 8; gg++) p2 |= part[gg][w];
        if ((i >> 6) == w) p2 &= ~(1ull << (i & 63));   // zero diagonal of A1@A1
        u64 a1 = rowA[w];
        u64 a2 = p2 & ~a1;
        u64 cl = a1 | a2;
        A2w[i * NW + w] = a2;
        CLw[i * NW + w] = cl;
        rowA2[w] = a2;
    }
    __syncthreads();
    float s1 = 0.f, s2 = 0.f;
    int d1 = 0, d2 = 0;
    for (int q = 0; q < 8; q++) {
        int j = q * 256 + t;
        float f = fit[(size_t)i * NN + j];
        int ww = j >> 6, b = j & 63;
        u64 a1 = rowA[ww], a2 = rowA2[ww];
        if ((a1 >> b) & 1) { s1 += f; d1++; }
        if ((a2 >> b) & 1) { s2 += f; d2++; }
    }
    for (int off = 32; off; off >>= 1) {
        s1 += __shfl_down(s1, off);
        s2 += __shfl_down(s2, off);
        d1 += __shfl_down(d1, off);
        d2 += __shfl_down(d2, off);
    }
    __shared__ float rs1[4], rs2[4];
    __shared__ int rd1[4], rd2[4];
    int wid = t >> 6, lane = t & 63;
    if (lane == 0) { rs1[wid] = s1; rs2[wid] = s2; rd1[wid] = d1; rd2[wid] = d2; }
    __syncthreads();
    if (t == 0) {
        float S1 = 0.f, S2 = 0.f; int D1 = 0, D2 = 0;
        for (int w2 = 0; w2 < 4; w2++) { S1 += rs1[w2]; S2 += rs2[w2]; D1 += rd1[w2]; D2 += rd2[w2]; }
        float v1 = D1 > 0 ? S1 / (float)D1 : 0.f;
        float v2 = D2 > 0 ? S2 / (float)D2 : 0.f;
        cs[i] = 0.5f * (v1 + v2);
    }
}

// ---------- fused: local extrema + colAny reduction ----------
__global__ __launch_bounds__(256) void k_extcol(const u64* __restrict__ A1w,
                                                const u64* __restrict__ CLw,
                                                const float* __restrict__ cs,
                                                unsigned char* is_c, u64* centerBits,
                                                u64* colAny) {
    int i = blockIdx.x, t = threadIdx.x;
    __shared__ u64 part[8][NW];
    if (i < 64) {
        int sub = t >> 5, w = t & 31;
        u64 acc = 0;
#pragma unroll
        for (int k = 0; k < 4; k++) {
            int r = i * 32 + sub + k * 8;
            acc |= CLw[(size_t)r * NW + w];
        }
        part[sub][w] = acc;
    }
    float ci = cs[i];
    int ok = 1;
    for (int q = 0; q < 8; q++) {
        int j = q * 256 + t;
        u64 a1 = A1w[i * NW + (j >> 6)];
        float other = ((a1 >> (j & 63)) & 1) ? cs[j] : 0.0f;
        ok &= ((ci - other) > 0.0f) ? 1 : 0;
    }
    int all = __syncthreads_and(ok);
    if (t == 0) {
        is_c[i] = (unsigned char)(all ? 1 : 0);
        if (all) atomicOr(&centerBits[i >> 6], 1ull << (i & 63));
    }
    if (i < 64 && t < NW) {
        u64 v = part[0][t];
#pragma unroll
        for (int s = 1; s < 8; s++) v |= part[s][t];
        atomicOr(&colAny[t], v);
    }
}

// ---------- pooled: sparse-column M^T @ emb, 16-deep prefetch gather ----------
__global__ __launch_bounds__(256) void k_pooled(const float* __restrict__ fit,
                                                const float* __restrict__ emb,
                                                const u64* __restrict__ CLw,
                                                const u64* __restrict__ centerBits,
                                                const u64* __restrict__ colAny,
                                                const unsigned char* __restrict__ is_c,
                                                float* __restrict__ out) {
    int j = blockIdx.x;
    int t = threadIdx.x;
    bool red = ((colAny[j >> 6] >> (j & 63)) & 1ull) == 0ull;
    for (int w = 0; w < NW; w++) red |= (CLw[(size_t)j * NW + w] & centerBits[w]) != 0ull;
    const float2* embj = reinterpret_cast<const float2*>(emb + (size_t)j * DD);
    float2* outj = reinterpret_cast<float2*>(out + (size_t)j * DD);
    bool active = is_c[j] && !red;
    if (!active) {
        float dg = red ? 0.0f : 1.0f;
        float2 v = embj[t];
        float2 o; o.x = v.x * dg; o.y = v.y * dg;
        outj[t] = o;
        return;
    }
    __shared__ int lidx[NN];
    __shared__ float lwt[NN];
    __shared__ int wcnt[4];
    int wid = t >> 6, lane = t & 63;
    int wsh = j >> 6;
    u64 bmask = 1ull << (j & 63);
    int total = 0;
    for (int qq = 0; qq < 8; qq++) {
        int i = qq * 256 + t;
        u64 cw = CLw[(size_t)i * NW + wsh];
        bool p = (cw & bmask) != 0ull;
        float f = 0.f;
        if (p) f = fit[(size_t)i * NN + j];
        u64 mask = __ballot(p);
        if (lane == 0) wcnt[wid] = __popcll(mask);
        __syncthreads();
        int off = total;
        for (int w = 0; w < wid; w++) off += wcnt[w];
        int tq = wcnt[0] + wcnt[1] + wcnt[2] + wcnt[3];
        if (p) {
            int pos = off + __popcll(mask & ((1ull << lane) - 1ull));
            lidx[pos] = i;
            lwt[pos] = f;
        }
        total += tq;
        __syncthreads();
    }
    float2 acc = {0.f, 0.f};
    int k = 0;
    for (; k + 16 <= total; k += 16) {
        int idxr[16];
        float wtr[16];
#pragma unroll
        for (int u = 0; u < 16; u++) { idxr[u] = lidx[k + u]; wtr[u] = lwt[k + u]; }
        float2 e[16];
#pragma unroll
        for (int u = 0; u < 16; u++)
            e[u] = reinterpret_cast<const float2*>(emb + (size_t)idxr[u] * DD)[t];
#pragma unroll
        for (int u = 0; u < 16; u++) {
            acc.x += wtr[u] * e[u].x;
            acc.y += wtr[u] * e[u].y;
        }
    }
    for (; k < total; k++) {
        int i = lidx[k];
        float w = lwt[k];
        float2 e = reinterpret_cast<const float2*>(emb + (size_t)i * DD)[t];
        acc.x += w * e.x;
        acc.y += w * e.y;
    }
    float2 v = embj[t];
    acc.x += v.x;
    acc.y += v.y;
    outj[t] = acc;
}

// ---------- launch ----------
extern "C" void kernel_launch(void* const* d_in, const int* in_sizes, int n_in,
                              void* d_out, int out_size, void* d_ws, size_t ws_size,
                              hipStream_t stream) {
    const float* emb = (const float*)d_in[0];
    const int*   ei  = (const int*)d_in[1];
    // d_in[2] = edge_matrix (A1 computed from edge_index directly)
    // d_in[3] = edge_matrix_weight (unused by reference math)
    const float* Wsc = (const float*)d_in[4];
    const float* bsc = (const float*)d_in[5];
    float* out = (float*)d_out;

    char* ws = (char*)d_ws;
    size_t off = 0;
    auto alloc = [&](size_t bytes) -> char* {
        char* p = ws + off;
        off = (off + bytes + 255) & ~(size_t)255;
        return p;
    };
    float*    fit = (float*)alloc((size_t)NN * NN * 4);        // 16 MB
    _Float16* zh  = (_Float16*)alloc((size_t)NN * DD * 2);     // 2 MB
    _Float16* zl  = (_Float16*)alloc((size_t)NN * DD * 2);     // 2 MB
    u64* A1w = (u64*)alloc((size_t)NN * NW * 8);               // 0.5 MB
    u64* A2w = (u64*)alloc((size_t)NN * NW * 8);
    u64* CLw = (u64*)alloc((size_t)NN * NW * 8);
    u64* centerBits = (u64*)alloc(NW * 8);
    u64* colAny     = (u64*)alloc(NW * 8);
    float* inv_norm = (float*)alloc(NN * 4);
    float* av   = (float*)alloc(NN * 4);
    float* cv   = (float*)alloc(NN * 4);
    float* ssum = (float*)alloc(NN * 4);
    float* cs   = (float*)alloc(NN * 4);
    unsigned char* is_c = (unsigned char*)alloc(NN);

    k_node<<<dim3(NN), dim3(256), 0, stream>>>(emb, Wsc, inv_norm, av, cv, zh, zl,
                                               ssum, centerBits, colAny, A1w);
    k_fitedge<<<dim3(528 + EE / 256), dim3(256), 0, stream>>>(zh, zl, fit,
                                                              ei, av, cv, bsc, ssum);
    k_edge_scatter<<<dim3(EE / 256), dim3(256), 0, stream>>>(ei, av, cv, bsc, ssum, fit);
    k_bits_e<<<dim3(EE / 256), dim3(256), 0, stream>>>(ei, fit, A1w);
    k_paths2s<<<dim3(NN), dim3(256), 0, stream>>>(A1w, fit, A2w, CLw, cs);
    k_extcol<<<dim3(NN), dim3(256), 0, stream>>>(A1w, CLw, cs, is_c, centerBits, colAny);
    k_pooled<<<dim3(NN), dim3(256), 0, stream>>>(fit, emb, CLw, centerBits, colAny, is_c, out);
}